// Round 1
// baseline (2130.189 us; speedup 1.0000x reference)
//
#include <hip/hip_runtime.h>
#include <math.h>
#include <stdint.h>

// Problem constants: B=8, P1=256 -> T=512 concat rows, C=1024, H=4096
#define TB_ 8
#define TT_ 512
#define TC_ 1024
#define TH_ 4096
static const int64_t WSB = 4194304; // elements per workspace buffer (B*T*C)

__device__ __forceinline__ float sigm(float x) { return 1.0f / (1.0f + expf(-x)); }

// LIF over 4 identical inputs, closed form of the reference scan.
__device__ __forceinline__ float lif4(float a) {
  float v = 0.0f, acc = 0.0f;
#pragma unroll
  for (int i = 0; i < 4; ++i) {
    v += (a - v) * 0.5f;            // v = v + (x - v)/TAU, TAU=2
    float s = (v >= 1.0f) ? 1.0f : 0.0f;  // spike at VTH=1
    acc += s;
    v *= (1.0f - s);
  }
  return acc * 0.25f;
}

// ---------------- elementwise kernels ----------------

// xc = concat([x, broadcast(rt)], axis=T). float4 over B*T*C/4 = 1048576.
__global__ __launch_bounds__(256) void build_xc(const float* __restrict__ x,
                                                const float* __restrict__ rt,
                                                float* __restrict__ xc) {
  int i = blockIdx.x * 256 + threadIdx.x;        // float4 index
  int c4 = i & 255;
  int t = (i >> 8) & 511;
  int b = i >> 17;
  float4 v;
  if (t < 256)
    v = ((const float4*)x)[(b * 256 + t) * 256 + c4];
  else
    v = ((const float4*)rt)[(t - 256) * 256 + c4];
  ((float4*)xc)[i] = v;
}

// LayerNorm each row of C=1024 floats. One block (256 thr) per row.
__global__ __launch_bounds__(256) void ln_rows(const float* __restrict__ src,
                                               float* __restrict__ dst) {
  __shared__ float red[256];
  int64_t row = blockIdx.x;
  const float4* s4 = (const float4*)(src + row * TC_);
  float4 v = s4[threadIdx.x];
  red[threadIdx.x] = v.x + v.y + v.z + v.w;
  __syncthreads();
  for (int off = 128; off > 0; off >>= 1) {
    if (threadIdx.x < off) red[threadIdx.x] += red[threadIdx.x + off];
    __syncthreads();
  }
  float mean = red[0] * (1.0f / 1024.0f);
  __syncthreads();
  float dx = v.x - mean, dy = v.y - mean, dz = v.z - mean, dw = v.w - mean;
  red[threadIdx.x] = dx * dx + dy * dy + dz * dz + dw * dw;
  __syncthreads();
  for (int off = 128; off > 0; off >>= 1) {
    if (threadIdx.x < off) red[threadIdx.x] += red[threadIdx.x + off];
    __syncthreads();
  }
  float rs = 1.0f / sqrtf(red[0] * (1.0f / 1024.0f) + 1e-6f);
  float4 o;
  o.x = dx * rs; o.y = dy * rs; o.z = dz * rs; o.w = dw * rs;
  ((float4*)(dst + row * TC_))[threadIdx.x] = o;
}

__device__ __forceinline__ float4 mixf4(float4 h, float4 s, float4 m) {
  float4 o;
  o.x = h.x * m.x + s.x * (1.0f - m.x);
  o.y = h.y * m.y + s.y * (1.0f - m.y);
  o.z = h.z * m.z + s.z * (1.0f - m.z);
  o.w = h.w * m.w + s.w * (1.0f - m.w);
  return o;
}

// time-mix blends (3 outputs). i over float4s of (B,T,C).
__global__ __launch_bounds__(256) void mix3(const float* __restrict__ ln,
                                            const float* __restrict__ tk,
                                            const float* __restrict__ tv,
                                            const float* __restrict__ tr,
                                            float* __restrict__ xk,
                                            float* __restrict__ xv,
                                            float* __restrict__ xr) {
  int i = blockIdx.x * 256 + threadIdx.x;
  int c4 = i & 255;
  int t = (i >> 8) & 511;
  float4 h = ((const float4*)ln)[i];
  float4 s = make_float4(0.f, 0.f, 0.f, 0.f);
  if (t > 0) s = ((const float4*)ln)[i - 256];
  ((float4*)xk)[i] = mixf4(h, s, ((const float4*)tk)[c4]);
  ((float4*)xv)[i] = mixf4(h, s, ((const float4*)tv)[c4]);
  ((float4*)xr)[i] = mixf4(h, s, ((const float4*)tr)[c4]);
}

__global__ __launch_bounds__(256) void mix2(const float* __restrict__ ln,
                                            const float* __restrict__ tk,
                                            const float* __restrict__ tr,
                                            float* __restrict__ xk,
                                            float* __restrict__ xr) {
  int i = blockIdx.x * 256 + threadIdx.x;
  int c4 = i & 255;
  int t = (i >> 8) & 511;
  float4 h = ((const float4*)ln)[i];
  float4 s = make_float4(0.f, 0.f, 0.f, 0.f);
  if (t > 0) s = ((const float4*)ln)[i - 256];
  ((float4*)xk)[i] = mixf4(h, s, ((const float4*)tk)[c4]);
  ((float4*)xr)[i] = mixf4(h, s, ((const float4*)tr)[c4]);
}

// wkv scan: one thread per (b,c) channel, sequential over T. Writes sr*y.
__global__ __launch_bounds__(256) void wkv_scan(const float* __restrict__ td,
                                                const float* __restrict__ tf,
                                                const float* __restrict__ K,
                                                const float* __restrict__ V,
                                                const float* __restrict__ SR,
                                                float* __restrict__ SRY) {
  int idx = blockIdx.x * 256 + threadIdx.x;  // 0..8191
  int c = idx & (TC_ - 1);
  int b = idx >> 10;
  float w = -expf(td[c]);
  float u = tf[c];
  float aa = 0.0f, bb = 0.0f, pp = -1e38f;
  int64_t base = (int64_t)b * TT_ * TC_ + c;
  for (int t = 0; t < TT_; ++t) {
    int64_t o = base + (int64_t)t * TC_;
    float kt = K[o], vt = V[o];
    float ww = u + kt;
    float p = fmaxf(pp, ww);
    float E1 = expf(pp - p);
    float E2 = expf(ww - p);
    float y = (E1 * aa + E2 * vt) / (E1 * bb + E2);
    SRY[o] = y * SR[o];
    float ww2 = pp + w;
    float p2 = fmaxf(ww2, kt);
    float f1 = expf(ww2 - p2);
    float f2 = expf(kt - p2);
    aa = f1 * aa + f2 * vt;
    bb = f1 * bb + f2;
    pp = p2;
  }
}

// xc += lif(a [* m]) ; float4 over B*T*C/4
__global__ __launch_bounds__(256) void lif_add(float* __restrict__ xc,
                                               const float* __restrict__ a,
                                               const float* __restrict__ m) {
  int i = blockIdx.x * 256 + threadIdx.x;
  float4 av = ((const float4*)a)[i];
  if (m) {
    float4 mv = ((const float4*)m)[i];
    av.x *= mv.x; av.y *= mv.y; av.z *= mv.z; av.w *= mv.w;
  }
  float4 xv = ((float4*)xc)[i];
  xv.x += lif4(av.x);
  xv.y += lif4(av.y);
  xv.z += lif4(av.z);
  xv.w += lif4(av.w);
  ((float4*)xc)[i] = xv;
}

// S[c] = sum_j Wam[c][j] (j<256). One 64-thread block per c.
__global__ __launch_bounds__(64) void row_sum256(const float* __restrict__ Wam,
                                                 float* __restrict__ S) {
  int c = blockIdx.x;
  int lane = threadIdx.x;
  float4 v = ((const float4*)(Wam + (int64_t)c * 256))[lane];
  float s = v.x + v.y + v.z + v.w;
  for (int off = 32; off > 0; off >>= 1) s += __shfl_down(s, off);
  if (lane == 0) S[c] = s;
}

// ---------------- GEMM: C[bz][m][n] = epi( sum_k A[m][k]*B[n][k] ) --------
// Both operands K-contiguous ("NT"). 64x64 tile, BK=16, 256 threads, 4x4/thread.
// EPI: 0 none, 1 sigmoid, 2 relu^2, 3 final (out = xo*(1+acc+brm[m]*S[n]+bam[n]))
template <int EPI>
__global__ __launch_bounds__(256) void gemm_nt(
    const float* __restrict__ A, const float* __restrict__ B,
    float* __restrict__ C, int M, int N, int K,
    int64_t sA, int64_t sB, int64_t sC,
    const float* __restrict__ e0, const float* __restrict__ e1,
    const float* __restrict__ e2, const float* __restrict__ e3, int64_t sE) {
  __shared__ __align__(16) float As[16][68];
  __shared__ __align__(16) float Bs[16][68];
  const int tid = threadIdx.x;
  const int bx = blockIdx.x, by = blockIdx.y, bz = blockIdx.z;
  const int tx = tid & 15, ty = tid >> 4;
  const int lrow = tid >> 2;        // 0..63
  const int lkq = (tid & 3) << 2;   // 0,4,8,12
  const float* Ab = A + bz * sA + (int64_t)(by * 64 + lrow) * K + lkq;
  const float* Bb = B + bz * sB + (int64_t)(bx * 64 + lrow) * K + lkq;
  float acc[4][4] = {};
  for (int k0 = 0; k0 < K; k0 += 16) {
    float4 a4 = *(const float4*)(Ab + k0);
    float4 b4 = *(const float4*)(Bb + k0);
    __syncthreads();  // previous tile fully consumed
    As[lkq + 0][lrow] = a4.x; As[lkq + 1][lrow] = a4.y;
    As[lkq + 2][lrow] = a4.z; As[lkq + 3][lrow] = a4.w;
    Bs[lkq + 0][lrow] = b4.x; Bs[lkq + 1][lrow] = b4.y;
    Bs[lkq + 2][lrow] = b4.z; Bs[lkq + 3][lrow] = b4.w;
    __syncthreads();
#pragma unroll
    for (int kk = 0; kk < 16; ++kk) {
      float4 av = *(const float4*)(&As[kk][ty * 4]);
      float4 bv = *(const float4*)(&Bs[kk][tx * 4]);
      float ar[4] = {av.x, av.y, av.z, av.w};
      float br[4] = {bv.x, bv.y, bv.z, bv.w};
#pragma unroll
      for (int i = 0; i < 4; ++i)
#pragma unroll
        for (int j = 0; j < 4; ++j) acc[i][j] = fmaf(ar[i], br[j], acc[i][j]);
    }
  }
  const int mBase = by * 64 + ty * 4;
  const int nBase = bx * 64 + tx * 4;
#pragma unroll
  for (int i = 0; i < 4; ++i) {
    int m = mBase + i;
    float vals[4];
#pragma unroll
    for (int j = 0; j < 4; ++j) {
      float v = acc[i][j];
      if (EPI == 1) {
        v = sigm(v);
      } else if (EPI == 2) {
        v = fmaxf(v, 0.0f);
        v = v * v;
      } else if (EPI == 3) {
        int n = nBase + j;
        float r2 = v + e0[m] * e1[n] + e2[n];
        float xo = e3[bz * sE + (int64_t)m * N + n];
        v = xo * (1.0f + r2);
      }
      vals[j] = v;
    }
    float4 o = make_float4(vals[0], vals[1], vals[2], vals[3]);
    *(float4*)(C + bz * sC + (int64_t)m * N + nBase) = o;
  }
}

// ---------------- launch ----------------
extern "C" void kernel_launch(void* const* d_in, const int* in_sizes, int n_in,
                              void* d_out, int out_size, void* d_ws,
                              size_t ws_size, hipStream_t stream) {
  const float* x   = (const float*)d_in[0];
  const float* rt  = (const float*)d_in[1];
  const float* td  = (const float*)d_in[2];
  const float* tf  = (const float*)d_in[3];
  const float* tmk = (const float*)d_in[4];
  const float* tmv = (const float*)d_in[5];
  const float* tmr = (const float*)d_in[6];
  const float* Wk  = (const float*)d_in[7];
  const float* Wv  = (const float*)d_in[8];
  const float* Wr  = (const float*)d_in[9];
  const float* Wo  = (const float*)d_in[10];
  const float* cmk = (const float*)d_in[11];
  const float* cmr = (const float*)d_in[12];
  const float* Wck = (const float*)d_in[13];
  const float* Wcv = (const float*)d_in[14];
  const float* Wcr = (const float*)d_in[15];
  const float* Wrm = (const float*)d_in[16];
  const float* brm = (const float*)d_in[17];
  const float* Wam = (const float*)d_in[18];
  const float* bam = (const float*)d_in[19];
  float* out = (float*)d_out;

  float* ws = (float*)d_ws;
  float* XC = ws;                // (B,T,C) residual stream
  float* LN = ws + 1 * WSB;      // layernorm output
  float* T0 = ws + 2 * WSB;
  float* T1 = ws + 3 * WSB;
  float* T2 = ws + 4 * WSB;
  float* T3 = ws + 5 * WSB;
  float* Sb = ws + 6 * WSB;      // 1024 floats

  dim3 blk(256);
  const int NV4 = 4096;  // blocks for 1048576 float4s

  // 1) xc = concat(x, rt); ln1
  build_xc<<<NV4, blk, 0, stream>>>(x, rt, XC);
  ln_rows<<<TB_ * TT_, blk, 0, stream>>>(XC, LN);
  // 2) time-mix blends
  mix3<<<NV4, blk, 0, stream>>>(LN, tmk, tmv, tmr, T0, T1, T2);
  // 3) r = sigmoid(xr@Wr^T) -> T3 ; k -> T2 ; v -> T0
  dim3 gMain(1024 / 64, 4096 / 64, 1);
  gemm_nt<1><<<gMain, blk, 0, stream>>>(T2, Wr, T3, 4096, 1024, 1024, 0, 0, 0,
                                        nullptr, nullptr, nullptr, nullptr, 0);
  gemm_nt<0><<<gMain, blk, 0, stream>>>(T0, Wk, T2, 4096, 1024, 1024, 0, 0, 0,
                                        nullptr, nullptr, nullptr, nullptr, 0);
  gemm_nt<0><<<gMain, blk, 0, stream>>>(T1, Wv, T0, 4096, 1024, 1024, 0, 0, 0,
                                        nullptr, nullptr, nullptr, nullptr, 0);
  // 4) wkv scan -> sry in T1
  wkv_scan<<<TB_ * TC_ / 256, blk, 0, stream>>>(td, tf, T2, T0, T3, T1);
  // 5) att = sry @ Wo^T -> T0 ; residual+LIF
  gemm_nt<0><<<gMain, blk, 0, stream>>>(T1, Wo, T0, 4096, 1024, 1024, 0, 0, 0,
                                        nullptr, nullptr, nullptr, nullptr, 0);
  lif_add<<<NV4, blk, 0, stream>>>(XC, T0, nullptr);
  // 6) ln2; channel-mix blends
  ln_rows<<<TB_ * TT_, blk, 0, stream>>>(XC, LN);
  mix2<<<NV4, blk, 0, stream>>>(LN, cmk, cmr, T0, T1);
  // 7) srr = sigmoid(xr2@Wcr^T) -> T2
  gemm_nt<1><<<gMain, blk, 0, stream>>>(T1, Wcr, T2, 4096, 1024, 1024, 0, 0, 0,
                                        nullptr, nullptr, nullptr, nullptr, 0);
  // 8) k2 = relu^2(xk2@Wck^T) (chunked, H intermediate in T3); kv -> T1
  for (int ch = 0; ch < 4; ++ch) {
    const float* Ach = T0 + (int64_t)ch * 1024 * 1024;
    gemm_nt<2><<<dim3(4096 / 64, 1024 / 64, 1), blk, 0, stream>>>(
        Ach, Wck, T3, 1024, 4096, 1024, 0, 0, 0, nullptr, nullptr, nullptr,
        nullptr, 0);
    gemm_nt<0><<<dim3(1024 / 64, 1024 / 64, 1), blk, 0, stream>>>(
        T3, Wcv, T1 + (int64_t)ch * 1024 * 1024, 1024, 1024, 4096, 0, 0, 0,
        nullptr, nullptr, nullptr, nullptr, 0);
  }
  // 9) ffn residual: xc += lif(srr * kv)
  lif_add<<<NV4, blk, 0, stream>>>(XC, T2, T1);
  // 10) tail: S[c] = sum_j Wam[c][j]
  row_sum256<<<1024, dim3(64), 0, stream>>>(Wam, Sb);
  // Mt[b][p][j] = sum_c Wrm[p][c] * rtok[b][j][c]   (rtok = XC rows 256..511)
  gemm_nt<0><<<dim3(4, 4, 8), blk, 0, stream>>>(
      Wrm, XC + 256 * 1024, T0, 256, 256, 1024, 0, (int64_t)512 * 1024,
      (int64_t)256 * 256, nullptr, nullptr, nullptr, nullptr, 0);
  // out[b][p][c] = xo*(1 + sum_j Mt[b][p][j]*Wam[c][j] + brm[p]*S[c] + bam[c])
  gemm_nt<3><<<dim3(16, 4, 8), blk, 0, stream>>>(
      T0, Wam, out, 256, 1024, 256, (int64_t)256 * 256, 0,
      (int64_t)256 * 1024, brm, Sb, bam, XC, (int64_t)512 * 1024);
}

// Round 2
// 515.417 us; speedup vs baseline: 4.1329x; 4.1329x over previous
//
#include <hip/hip_runtime.h>
#include <hip/hip_bf16.h>
#include <math.h>
#include <stdint.h>

// B=8, P1=256 -> T=512 concat rows, C=1024, H=4096
#define TB_ 8
#define TT_ 512
#define TC_ 1024

typedef __attribute__((ext_vector_type(8))) short bf16x8;
typedef __attribute__((ext_vector_type(4))) short s16x4;
typedef __attribute__((ext_vector_type(4))) float f32x4;

__device__ __forceinline__ float b2f(short u) {
  union { unsigned int i; float f; } x;
  x.i = ((unsigned int)(unsigned short)u) << 16;
  return x.f;
}
__device__ __forceinline__ short f2b(float f) {
  __hip_bfloat16 h = __float2bfloat16(f);  // RNE
  return __builtin_bit_cast(short, h);
}
__device__ __forceinline__ float sigm(float x) { return 1.0f / (1.0f + expf(-x)); }

// LIF over 4 identical inputs (closed form of the reference scan), TAU=2, VTH=1
__device__ __forceinline__ float lif4(float a) {
  float v = 0.0f, acc = 0.0f;
#pragma unroll
  for (int i = 0; i < 4; ++i) {
    v += (a - v) * 0.5f;
    float s = (v >= 1.0f) ? 1.0f : 0.0f;
    acc += s;
    v *= (1.0f - s);
  }
  return acc * 0.25f;
}

__device__ __forceinline__ void gload16(const void* g, void* l) {
  __builtin_amdgcn_global_load_lds(
      (__attribute__((address_space(1))) void*)(g),
      (__attribute__((address_space(3))) void*)(l), 16, 0, 0);
}

// ---------------- elementwise kernels ----------------

__global__ __launch_bounds__(256) void build_xc(const float* __restrict__ x,
                                                const float* __restrict__ rt,
                                                float* __restrict__ xc) {
  int i = blockIdx.x * 256 + threadIdx.x;  // float4 index over B*T*C/4
  int c4 = i & 255;
  int t = (i >> 8) & 511;
  int b = i >> 17;
  float4 v;
  if (t < 256)
    v = ((const float4*)x)[(b * 256 + t) * 256 + c4];
  else
    v = ((const float4*)rt)[(t - 256) * 256 + c4];
  ((float4*)xc)[i] = v;
}

// LayerNorm each row (C=1024 f32) -> bf16. One 256-thread block per row.
__global__ __launch_bounds__(256) void ln_rows_b(const float* __restrict__ src,
                                                 short* __restrict__ dst) {
  __shared__ float red[256];
  int64_t row = blockIdx.x;
  float4 v = ((const float4*)(src + row * TC_))[threadIdx.x];
  red[threadIdx.x] = v.x + v.y + v.z + v.w;
  __syncthreads();
  for (int off = 128; off > 0; off >>= 1) {
    if (threadIdx.x < off) red[threadIdx.x] += red[threadIdx.x + off];
    __syncthreads();
  }
  float mean = red[0] * (1.0f / 1024.0f);
  __syncthreads();
  float dx = v.x - mean, dy = v.y - mean, dz = v.z - mean, dw = v.w - mean;
  red[threadIdx.x] = dx * dx + dy * dy + dz * dz + dw * dw;
  __syncthreads();
  for (int off = 128; off > 0; off >>= 1) {
    if (threadIdx.x < off) red[threadIdx.x] += red[threadIdx.x + off];
    __syncthreads();
  }
  float rs = 1.0f / sqrtf(red[0] * (1.0f / 1024.0f) + 1e-6f);
  s16x4 o;
  o.x = f2b(dx * rs); o.y = f2b(dy * rs); o.z = f2b(dz * rs); o.w = f2b(dw * rs);
  *(s16x4*)(dst + row * TC_ + threadIdx.x * 4) = o;
}

// time-mix blends from bf16 LN. 8 elems/thread; i over B*T*C/8.
__global__ __launch_bounds__(256) void mix3_b(const short* __restrict__ ln,
                                              const float* __restrict__ tk,
                                              const float* __restrict__ tv,
                                              const float* __restrict__ tr,
                                              short* __restrict__ xk,
                                              short* __restrict__ xv,
                                              short* __restrict__ xr) {
  int i = blockIdx.x * 256 + threadIdx.x;  // short8 index
  int c8 = i & 127;
  int t = (i >> 7) & 511;
  bf16x8 h = *(const bf16x8*)(ln + (int64_t)i * 8);
  bf16x8 s = {};
  if (t > 0) s = *(const bf16x8*)(ln + (int64_t)(i - 128) * 8);
  bf16x8 ok, ov, orr;
#pragma unroll
  for (int e = 0; e < 8; ++e) {
    float hf = b2f(h[e]), sf = b2f(s[e]);
    int c = c8 * 8 + e;
    float mk = tk[c], mv = tv[c], mr = tr[c];
    ok[e] = f2b(hf * mk + sf * (1.0f - mk));
    ov[e] = f2b(hf * mv + sf * (1.0f - mv));
    orr[e] = f2b(hf * mr + sf * (1.0f - mr));
  }
  *(bf16x8*)(xk + (int64_t)i * 8) = ok;
  *(bf16x8*)(xv + (int64_t)i * 8) = ov;
  *(bf16x8*)(xr + (int64_t)i * 8) = orr;
}

__global__ __launch_bounds__(256) void mix2_b(const short* __restrict__ ln,
                                              const float* __restrict__ tk,
                                              const float* __restrict__ tr,
                                              short* __restrict__ xk,
                                              short* __restrict__ xr) {
  int i = blockIdx.x * 256 + threadIdx.x;
  int c8 = i & 127;
  int t = (i >> 7) & 511;
  bf16x8 h = *(const bf16x8*)(ln + (int64_t)i * 8);
  bf16x8 s = {};
  if (t > 0) s = *(const bf16x8*)(ln + (int64_t)(i - 128) * 8);
  bf16x8 ok, orr;
#pragma unroll
  for (int e = 0; e < 8; ++e) {
    float hf = b2f(h[e]), sf = b2f(s[e]);
    int c = c8 * 8 + e;
    float mk = tk[c], mr = tr[c];
    ok[e] = f2b(hf * mk + sf * (1.0f - mk));
    orr[e] = f2b(hf * mr + sf * (1.0f - mr));
  }
  *(bf16x8*)(xk + (int64_t)i * 8) = ok;
  *(bf16x8*)(xr + (int64_t)i * 8) = orr;
}

// f32 -> bf16, 8 elems/thread
__global__ __launch_bounds__(256) void cvt_b(const float* __restrict__ src,
                                             short* __restrict__ dst) {
  int64_t i = (int64_t)(blockIdx.x * 256 + threadIdx.x) * 8;
  float4 a = *(const float4*)(src + i);
  float4 b = *(const float4*)(src + i + 4);
  bf16x8 o;
  o[0] = f2b(a.x); o[1] = f2b(a.y); o[2] = f2b(a.z); o[3] = f2b(a.w);
  o[4] = f2b(b.x); o[5] = f2b(b.y); o[6] = f2b(b.z); o[7] = f2b(b.w);
  *(bf16x8*)(dst + i) = o;
}

// rtok rows (per b: rows 256..511 of XC) f32 -> bf16 contiguous (B,256,C)
__global__ __launch_bounds__(256) void cvt_rtok(const float* __restrict__ xc,
                                                short* __restrict__ dst) {
  int i = blockIdx.x * 256 + threadIdx.x;  // short8 idx over 8*256*1024/8
  int b = i >> 15;
  int rem = i & 32767;
  const float* s = xc + (int64_t)b * 524288 + 262144 + (int64_t)rem * 8;
  float4 a = *(const float4*)s;
  float4 c = *(const float4*)(s + 4);
  bf16x8 o;
  o[0] = f2b(a.x); o[1] = f2b(a.y); o[2] = f2b(a.z); o[3] = f2b(a.w);
  o[4] = f2b(c.x); o[5] = f2b(c.y); o[6] = f2b(c.z); o[7] = f2b(c.w);
  *(bf16x8*)(dst + (int64_t)i * 8) = o;
}

// wkv scan, bf16 inputs/outputs, one thread per (b,c)
__global__ __launch_bounds__(256) void wkv_scan_b(const float* __restrict__ td,
                                                  const float* __restrict__ tf,
                                                  const short* __restrict__ K,
                                                  const short* __restrict__ V,
                                                  const short* __restrict__ SR,
                                                  short* __restrict__ SRY) {
  int idx = blockIdx.x * 256 + threadIdx.x;  // 0..8191
  int c = idx & (TC_ - 1);
  int b = idx >> 10;
  float w = -expf(td[c]);
  float u = tf[c];
  float aa = 0.0f, bb = 0.0f, pp = -1e38f;
  int64_t base = (int64_t)b * TT_ * TC_ + c;
  for (int t = 0; t < TT_; ++t) {
    int64_t o = base + (int64_t)t * TC_;
    float kt = b2f(K[o]), vt = b2f(V[o]);
    float ww = u + kt;
    float p = fmaxf(pp, ww);
    float E1 = expf(pp - p);
    float E2 = expf(ww - p);
    float y = (E1 * aa + E2 * vt) / (E1 * bb + E2);
    SRY[o] = f2b(y * b2f(SR[o]));
    float ww2 = pp + w;
    float p2 = fmaxf(ww2, kt);
    float f1 = expf(ww2 - p2);
    float f2_ = expf(kt - p2);
    aa = f1 * aa + f2_ * vt;
    bb = f1 * bb + f2_;
    pp = p2;
  }
}

// S[c] = sum_j Wam[c][j] (j<256)
__global__ __launch_bounds__(64) void row_sum256(const float* __restrict__ Wam,
                                                 float* __restrict__ S) {
  int c = blockIdx.x;
  int lane = threadIdx.x;
  float4 v = ((const float4*)(Wam + (int64_t)c * 256))[lane];
  float s = v.x + v.y + v.z + v.w;
  for (int off = 32; off > 0; off >>= 1) s += __shfl_down(s, off);
  if (lane == 0) S[c] = s;
}

// ---------------- bf16 MFMA GEMM ----------------
// C[bz][m][n] = epi( sum_k A[m][k]*B[n][k] ), A: M x K bf16, B: N x K bf16.
// 128x128 tile, BK=32, 256 threads (4 waves, 2x2), 4x4 frags of 16x16x32/wave.
// EPI: 0 -> bf16 out; 1 sigmoid -> bf16; 2 relu^2 -> bf16;
//      3 tail-final -> f32 out (e0=brm[m], e1=S[n], e2=bam[n], e3=XC f32, sE);
//      4 C(f32) = C + lif4(acc)                 (C = XC, in/out)
//      5 C(f32) = C + lif4(acc * e3[m][n])      (e3 = SRR bf16)
template <int EPI>
__global__ __launch_bounds__(256, 2) void gemm_bf16(
    const short* __restrict__ A, const short* __restrict__ B,
    void* __restrict__ Cp, int M, int N, int K,
    int64_t sA, int64_t sB, int64_t sC,
    const float* __restrict__ e0, const float* __restrict__ e1,
    const float* __restrict__ e2, const void* __restrict__ e3, int64_t sE) {
  __shared__ short lds[8192];  // A: [0,4096) shorts, B: [4096,8192)
  const int tid = threadIdx.x;
  const int bz = blockIdx.z;
  const int brow = blockIdx.y * 128;
  const int bcol = blockIdx.x * 128;
  const short* Ab = A + bz * sA;
  const short* Bb = B + bz * sB;

  // staging addresses (chunk q = tid, tid+256; row=q>>2, kc=q&3)
  const short* gA0 = Ab + (int64_t)(brow + (tid >> 2)) * K + (tid & 3) * 8;
  const short* gA1 = Ab + (int64_t)(brow + 64 + (tid >> 2)) * K + (tid & 3) * 8;
  const short* gB0 = Bb + (int64_t)(bcol + (tid >> 2)) * K + (tid & 3) * 8;
  const short* gB1 = Bb + (int64_t)(bcol + 64 + (tid >> 2)) * K + (tid & 3) * 8;
  short* lA0 = &lds[tid * 8];
  short* lA1 = &lds[2048 + tid * 8];
  short* lB0 = &lds[4096 + tid * 8];
  short* lB1 = &lds[6144 + tid * 8];

  const int lane = tid & 63, wid = tid >> 6;
  const int wr = wid >> 1, wc = wid & 1;
  const short* aPtr = lds + (wr * 64 + (lane & 15)) * 32 + (lane >> 4) * 8;
  const short* bPtr = lds + 4096 + (wc * 64 + (lane & 15)) * 32 + (lane >> 4) * 8;

  f32x4 acc[4][4] = {};
  for (int k0 = 0; k0 < K; k0 += 32) {
    gload16(gA0 + k0, lA0);
    gload16(gA1 + k0, lA1);
    gload16(gB0 + k0, lB0);
    gload16(gB1 + k0, lB1);
    __syncthreads();  // drains vmcnt -> tiles visible
    bf16x8 af[4], bfv[4];
#pragma unroll
    for (int m = 0; m < 4; ++m) af[m] = *(const bf16x8*)(aPtr + m * 512);
#pragma unroll
    for (int n = 0; n < 4; ++n) bfv[n] = *(const bf16x8*)(bPtr + n * 512);
#pragma unroll
    for (int m = 0; m < 4; ++m)
#pragma unroll
      for (int n = 0; n < 4; ++n)
        acc[m][n] = __builtin_amdgcn_mfma_f32_16x16x32_bf16(af[m], bfv[n],
                                                            acc[m][n], 0, 0, 0);
    __syncthreads();  // tiles consumed before next stage
  }

  const int r0 = brow + wr * 64 + (lane >> 4) * 4;
  const int c0 = bcol + wc * 64 + (lane & 15);
#pragma unroll
  for (int m = 0; m < 4; ++m) {
#pragma unroll
    for (int j = 0; j < 4; ++j) {
      int row = r0 + m * 16 + j;
#pragma unroll
      for (int n = 0; n < 4; ++n) {
        int col = c0 + n * 16;
        float v = acc[m][n][j];
        int64_t idx = (int64_t)row * N + col;
        if (EPI == 0) {
          ((short*)Cp)[bz * sC + idx] = f2b(v);
        } else if (EPI == 1) {
          ((short*)Cp)[bz * sC + idx] = f2b(sigm(v));
        } else if (EPI == 2) {
          v = fmaxf(v, 0.0f);
          ((short*)Cp)[bz * sC + idx] = f2b(v * v);
        } else if (EPI == 3) {
          float r2 = v + e0[row] * e1[col] + e2[col];
          float xo = ((const float*)e3)[bz * sE + idx];
          ((float*)Cp)[bz * sC + idx] = xo * (1.0f + r2);
        } else if (EPI == 4) {
          float* XC = (float*)Cp;
          XC[idx] = XC[idx] + lif4(v);
        } else if (EPI == 5) {
          float* XC = (float*)Cp;
          float srr = b2f(((const short*)e3)[idx]);
          XC[idx] = XC[idx] + lif4(v * srr);
        }
      }
    }
  }
}

// ---------------- launch ----------------
extern "C" void kernel_launch(void* const* d_in, const int* in_sizes, int n_in,
                              void* d_out, int out_size, void* d_ws,
                              size_t ws_size, hipStream_t stream) {
  const float* x   = (const float*)d_in[0];
  const float* rt  = (const float*)d_in[1];
  const float* td  = (const float*)d_in[2];
  const float* tf  = (const float*)d_in[3];
  const float* tmk = (const float*)d_in[4];
  const float* tmv = (const float*)d_in[5];
  const float* tmr = (const float*)d_in[6];
  const float* Wk  = (const float*)d_in[7];
  const float* Wv  = (const float*)d_in[8];
  const float* Wr  = (const float*)d_in[9];
  const float* Wo  = (const float*)d_in[10];
  const float* cmk = (const float*)d_in[11];
  const float* cmr = (const float*)d_in[12];
  const float* Wck = (const float*)d_in[13];
  const float* Wcv = (const float*)d_in[14];
  const float* Wcr = (const float*)d_in[15];
  const float* Wrm = (const float*)d_in[16];
  const float* brm = (const float*)d_in[17];
  const float* Wam = (const float*)d_in[18];
  const float* bam = (const float*)d_in[19];
  float* out = (float*)d_out;

  const size_t MB = 1ull << 20;
  uint8_t* W8 = (uint8_t*)d_ws;
  float* XC  = (float*)(W8);                 // 16 MB f32 residual
  short* L   = (short*)(W8 + 16 * MB);       // 8 MB bf16 slots
  short* S1  = (short*)(W8 + 24 * MB);
  short* S2  = (short*)(W8 + 32 * MB);
  short* S3  = (short*)(W8 + 40 * MB);
  short* S4  = (short*)(W8 + 48 * MB);
  short* bWk  = (short*)(W8 + 56 * MB);      // time-mix weights (2 MB each)
  short* bWv  = (short*)(W8 + 58 * MB);
  short* bWr  = (short*)(W8 + 60 * MB);
  short* bWo  = (short*)(W8 + 62 * MB);
  short* bWcr = (short*)(W8 + 64 * MB);
  short* bWrm = (short*)(W8 + 66 * MB);            // 0.5 MB
  short* bWam = (short*)(W8 + 66 * MB + 512 * 1024);  // 0.5 MB
  short* bWck = bWk;                         // overwrites bWk..bWo (8 MB) later
  short* bWcv = S4;                          // reuses slot S4 later
  short* H16  = (short*)(W8 + 67 * MB);      // 32 MB bf16 (4096x4096)
  float* Sb   = (float*)(W8 + 99 * MB);      // 4 KB

  dim3 blk(256);
  const int NV4 = 4096;   // B*T*C/4 / 256
  const int NV8 = 2048;   // B*T*C/8 / 256

  // weight conversions needed for time-mix + tail
  cvt_b<<<512, blk, 0, stream>>>(Wk, bWk);
  cvt_b<<<512, blk, 0, stream>>>(Wv, bWv);
  cvt_b<<<512, blk, 0, stream>>>(Wr, bWr);
  cvt_b<<<512, blk, 0, stream>>>(Wo, bWo);
  cvt_b<<<512, blk, 0, stream>>>(Wcr, bWcr);
  cvt_b<<<128, blk, 0, stream>>>(Wrm, bWrm);
  cvt_b<<<128, blk, 0, stream>>>(Wam, bWam);

  // 1) xc = concat(x, rt); ln1 -> L; mixes -> S1,S2,S3
  build_xc<<<NV4, blk, 0, stream>>>(x, rt, XC);
  ln_rows_b<<<TB_ * TT_, blk, 0, stream>>>(XC, L);
  mix3_b<<<NV8, blk, 0, stream>>>(L, tmk, tmv, tmr, S1, S2, S3);

  // 2) K = S1*Wk^T -> S4 ; V = S2*Wv^T -> S1 ; SR = sigm(S3*Wr^T) -> S2
  dim3 gMain(1024 / 128, 4096 / 128, 1);
  gemm_bf16<0><<<gMain, blk, 0, stream>>>(S1, bWk, S4, 4096, 1024, 1024, 0, 0, 0,
                                          nullptr, nullptr, nullptr, nullptr, 0);
  gemm_bf16<0><<<gMain, blk, 0, stream>>>(S2, bWv, S1, 4096, 1024, 1024, 0, 0, 0,
                                          nullptr, nullptr, nullptr, nullptr, 0);
  gemm_bf16<1><<<gMain, blk, 0, stream>>>(S3, bWr, S2, 4096, 1024, 1024, 0, 0, 0,
                                          nullptr, nullptr, nullptr, nullptr, 0);
  // 3) wkv -> SRY in L
  wkv_scan_b<<<TB_ * TC_ / 256, blk, 0, stream>>>(td, tf, S4, S1, S2, L);
  // 4) att: XC += lif(L*Wo^T)
  gemm_bf16<4><<<gMain, blk, 0, stream>>>(L, bWo, XC, 4096, 1024, 1024, 0, 0, 0,
                                          nullptr, nullptr, nullptr, nullptr, 0);
  // 5) ln2 -> L; mix2 -> S1(xk2), S2(xr2)
  ln_rows_b<<<TB_ * TT_, blk, 0, stream>>>(XC, L);
  mix2_b<<<NV8, blk, 0, stream>>>(L, cmk, cmr, S1, S2);
  // 6) SRR = sigm(S2*Wcr^T) -> S3
  gemm_bf16<1><<<gMain, blk, 0, stream>>>(S2, bWcr, S3, 4096, 1024, 1024, 0, 0, 0,
                                          nullptr, nullptr, nullptr, nullptr, 0);
  // 7) convert channel-mix weights into now-dead regions
  cvt_b<<<2048, blk, 0, stream>>>(Wck, bWck);
  cvt_b<<<2048, blk, 0, stream>>>(Wcv, bWcv);
  // 8) H = relu^2(S1*Wck^T) -> H16 (4096x4096)
  gemm_bf16<2><<<dim3(32, 32, 1), blk, 0, stream>>>(
      S1, bWck, H16, 4096, 4096, 1024, 0, 0, 0, nullptr, nullptr, nullptr,
      nullptr, 0);
  // 9) XC += lif(SRR * (H*Wcv^T))
  gemm_bf16<5><<<dim3(8, 32, 1), blk, 0, stream>>>(
      H16, bWcv, XC, 4096, 1024, 4096, 0, 0, 0, nullptr, nullptr, nullptr, S3,
      0);
  // 10) tail
  cvt_rtok<<<1024, blk, 0, stream>>>(XC, S1);
  gemm_bf16<0><<<dim3(2, 2, 8), blk, 0, stream>>>(
      bWrm, S1, S2, 256, 256, 1024, 0, (int64_t)256 * 1024, (int64_t)256 * 256,
      nullptr, nullptr, nullptr, nullptr, 0);
  row_sum256<<<1024, dim3(64), 0, stream>>>(Wam, Sb);
  gemm_bf16<3><<<dim3(8, 2, 8), blk, 0, stream>>>(
      S2, bWam, out, 256, 1024, 256, (int64_t)256 * 256, 0,
      (int64_t)256 * 1024, brm, Sb, bam, XC, (int64_t)512 * 1024);
}

// Round 3
// 400.830 us; speedup vs baseline: 5.3144x; 1.2859x over previous
//
#include <hip/hip_runtime.h>
#include <hip/hip_bf16.h>
#include <math.h>
#include <stdint.h>

// B=8, P1=256 -> T=512 concat rows, C=1024, H=4096
#define TB_ 8
#define TT_ 512
#define TC_ 1024
// wkv chunked scan: 32 chunks of 16 steps
#define WKV_NCH 32
#define WKV_L 16

typedef __attribute__((ext_vector_type(8))) short bf16x8;
typedef __attribute__((ext_vector_type(4))) short s16x4;
typedef __attribute__((ext_vector_type(4))) float f32x4;

__device__ __forceinline__ float b2f(short u) {
  union { unsigned int i; float f; } x;
  x.i = ((unsigned int)(unsigned short)u) << 16;
  return x.f;
}
__device__ __forceinline__ short f2b(float f) {
  __hip_bfloat16 h = __float2bfloat16(f);  // RNE
  return __builtin_bit_cast(short, h);
}
__device__ __forceinline__ float sigm(float x) { return 1.0f / (1.0f + expf(-x)); }

// LIF over 4 identical inputs (closed form of the reference scan), TAU=2, VTH=1
__device__ __forceinline__ float lif4(float a) {
  float v = 0.0f, acc = 0.0f;
#pragma unroll
  for (int i = 0; i < 4; ++i) {
    v += (a - v) * 0.5f;
    float s = (v >= 1.0f) ? 1.0f : 0.0f;
    acc += s;
    v *= (1.0f - s);
  }
  return acc * 0.25f;
}

__device__ __forceinline__ void gload16(const void* g, void* l) {
  __builtin_amdgcn_global_load_lds(
      (__attribute__((address_space(1))) void*)(g),
      (__attribute__((address_space(3))) void*)(l), 16, 0, 0);
}

// ---------------- elementwise kernels ----------------

__global__ __launch_bounds__(256) void build_xc(const float* __restrict__ x,
                                                const float* __restrict__ rt,
                                                float* __restrict__ xc) {
  int i = blockIdx.x * 256 + threadIdx.x;  // float4 index over B*T*C/4
  int c4 = i & 255;
  int t = (i >> 8) & 511;
  int b = i >> 17;
  float4 v;
  if (t < 256)
    v = ((const float4*)x)[(b * 256 + t) * 256 + c4];
  else
    v = ((const float4*)rt)[(t - 256) * 256 + c4];
  ((float4*)xc)[i] = v;
}

// LayerNorm each row (C=1024 f32) -> bf16. One 256-thread block per row.
__global__ __launch_bounds__(256) void ln_rows_b(const float* __restrict__ src,
                                                 short* __restrict__ dst) {
  __shared__ float red[256];
  int64_t row = blockIdx.x;
  float4 v = ((const float4*)(src + row * TC_))[threadIdx.x];
  red[threadIdx.x] = v.x + v.y + v.z + v.w;
  __syncthreads();
  for (int off = 128; off > 0; off >>= 1) {
    if (threadIdx.x < off) red[threadIdx.x] += red[threadIdx.x + off];
    __syncthreads();
  }
  float mean = red[0] * (1.0f / 1024.0f);
  __syncthreads();
  float dx = v.x - mean, dy = v.y - mean, dz = v.z - mean, dw = v.w - mean;
  red[threadIdx.x] = dx * dx + dy * dy + dz * dz + dw * dw;
  __syncthreads();
  for (int off = 128; off > 0; off >>= 1) {
    if (threadIdx.x < off) red[threadIdx.x] += red[threadIdx.x + off];
    __syncthreads();
  }
  float rs = 1.0f / sqrtf(red[0] * (1.0f / 1024.0f) + 1e-6f);
  s16x4 o;
  o.x = f2b(dx * rs); o.y = f2b(dy * rs); o.z = f2b(dz * rs); o.w = f2b(dw * rs);
  *(s16x4*)(dst + row * TC_ + threadIdx.x * 4) = o;
}

// time-mix blends from bf16 LN. 8 elems/thread; i over B*T*C/8.
__global__ __launch_bounds__(256) void mix3_b(const short* __restrict__ ln,
                                              const float* __restrict__ tk,
                                              const float* __restrict__ tv,
                                              const float* __restrict__ tr,
                                              short* __restrict__ xk,
                                              short* __restrict__ xv,
                                              short* __restrict__ xr) {
  int i = blockIdx.x * 256 + threadIdx.x;  // short8 index
  int c8 = i & 127;
  int t = (i >> 7) & 511;
  bf16x8 h = *(const bf16x8*)(ln + (int64_t)i * 8);
  bf16x8 s = {};
  if (t > 0) s = *(const bf16x8*)(ln + (int64_t)(i - 128) * 8);
  bf16x8 ok, ov, orr;
#pragma unroll
  for (int e = 0; e < 8; ++e) {
    float hf = b2f(h[e]), sf = b2f(s[e]);
    int c = c8 * 8 + e;
    float mk = tk[c], mv = tv[c], mr = tr[c];
    ok[e] = f2b(hf * mk + sf * (1.0f - mk));
    ov[e] = f2b(hf * mv + sf * (1.0f - mv));
    orr[e] = f2b(hf * mr + sf * (1.0f - mr));
  }
  *(bf16x8*)(xk + (int64_t)i * 8) = ok;
  *(bf16x8*)(xv + (int64_t)i * 8) = ov;
  *(bf16x8*)(xr + (int64_t)i * 8) = orr;
}

__global__ __launch_bounds__(256) void mix2_b(const short* __restrict__ ln,
                                              const float* __restrict__ tk,
                                              const float* __restrict__ tr,
                                              short* __restrict__ xk,
                                              short* __restrict__ xr) {
  int i = blockIdx.x * 256 + threadIdx.x;
  int c8 = i & 127;
  int t = (i >> 7) & 511;
  bf16x8 h = *(const bf16x8*)(ln + (int64_t)i * 8);
  bf16x8 s = {};
  if (t > 0) s = *(const bf16x8*)(ln + (int64_t)(i - 128) * 8);
  bf16x8 ok, orr;
#pragma unroll
  for (int e = 0; e < 8; ++e) {
    float hf = b2f(h[e]), sf = b2f(s[e]);
    int c = c8 * 8 + e;
    float mk = tk[c], mr = tr[c];
    ok[e] = f2b(hf * mk + sf * (1.0f - mk));
    orr[e] = f2b(hf * mr + sf * (1.0f - mr));
  }
  *(bf16x8*)(xk + (int64_t)i * 8) = ok;
  *(bf16x8*)(xr + (int64_t)i * 8) = orr;
}

// f32 -> bf16, 8 elems/thread
__global__ __launch_bounds__(256) void cvt_b(const float* __restrict__ src,
                                             short* __restrict__ dst) {
  int64_t i = (int64_t)(blockIdx.x * 256 + threadIdx.x) * 8;
  float4 a = *(const float4*)(src + i);
  float4 b = *(const float4*)(src + i + 4);
  bf16x8 o;
  o[0] = f2b(a.x); o[1] = f2b(a.y); o[2] = f2b(a.z); o[3] = f2b(a.w);
  o[4] = f2b(b.x); o[5] = f2b(b.y); o[6] = f2b(b.z); o[7] = f2b(b.w);
  *(bf16x8*)(dst + i) = o;
}

// rtok rows (per b: rows 256..511 of XC) f32 -> bf16 contiguous (B,256,C)
__global__ __launch_bounds__(256) void cvt_rtok(const float* __restrict__ xc,
                                                short* __restrict__ dst) {
  int i = blockIdx.x * 256 + threadIdx.x;  // short8 idx
  int b = i >> 15;
  int rem = i & 32767;
  const float* s = xc + (int64_t)b * 524288 + 262144 + (int64_t)rem * 8;
  float4 a = *(const float4*)s;
  float4 c = *(const float4*)(s + 4);
  bf16x8 o;
  o[0] = f2b(a.x); o[1] = f2b(a.y); o[2] = f2b(a.z); o[3] = f2b(a.w);
  o[4] = f2b(c.x); o[5] = f2b(c.y); o[6] = f2b(c.z); o[7] = f2b(c.w);
  *(bf16x8*)(dst + (int64_t)i * 8) = o;
}

// ---------------- wkv chunked parallel scan ----------------
// Phase 1: per (chunk, b, c) run chunk from zero state -> (Ca, Da, Qa).
// Layout of all scan arrays: [ch][b*1024+c], SC=8192 entries per plane.
__global__ __launch_bounds__(256) void wkv_p1(const float* __restrict__ td,
                                              const short* __restrict__ K,
                                              const short* __restrict__ V,
                                              float* __restrict__ Ca,
                                              float* __restrict__ Da,
                                              float* __restrict__ Qa) {
  int bx = blockIdx.x;              // [ch:5][b:3][cg:2]
  int ch = bx >> 5;
  int b = (bx >> 2) & 7;
  int c = (bx & 3) * 256 + threadIdx.x;
  float w = -expf(td[c]);
  float aa = 0.0f, bb = 0.0f, pp = -1e38f;
  int64_t base = ((int64_t)b * TT_ + ch * WKV_L) * TC_ + c;
#pragma unroll
  for (int t = 0; t < WKV_L; ++t) {
    int64_t o = base + (int64_t)t * TC_;
    float kt = b2f(K[o]), vt = b2f(V[o]);
    float ww2 = pp + w;
    float p2 = fmaxf(ww2, kt);
    float e1 = expf(ww2 - p2);
    float e2 = expf(kt - p2);
    aa = e1 * aa + e2 * vt;
    bb = e1 * bb + e2;
    pp = p2;
  }
  int idx = ch * 8192 + b * 1024 + c;
  Ca[idx] = aa; Da[idx] = bb; Qa[idx] = pp;
}

// Phase 2: per (b,c) compose chunk transforms sequentially; store each
// chunk's INCOMING state into (Aa, Ba, Pa).
__global__ __launch_bounds__(256) void wkv_p2(const float* __restrict__ td,
                                              const float* __restrict__ Ca,
                                              const float* __restrict__ Da,
                                              const float* __restrict__ Qa,
                                              float* __restrict__ Aa,
                                              float* __restrict__ Ba,
                                              float* __restrict__ Pa) {
  int i = blockIdx.x * 256 + threadIdx.x;  // 0..8191 = b*1024+c
  int c = i & (TC_ - 1);
  float wL = -expf(td[c]) * (float)WKV_L;
  float aa = 0.0f, bb = 0.0f, pp = -1e38f;
#pragma unroll 4
  for (int ch = 0; ch < WKV_NCH; ++ch) {
    int idx = ch * 8192 + i;
    Aa[idx] = aa; Ba[idx] = bb; Pa[idx] = pp;
    float ppw = pp + wL;
    float q = Qa[idx];
    float p2 = fmaxf(ppw, q);
    float ea = expf(ppw - p2);
    float eb = expf(q - p2);
    aa = aa * ea + Ca[idx] * eb;
    bb = bb * ea + Da[idx] * eb;
    pp = p2;
  }
}

// Phase 3: per (chunk, b, c) replay chunk from incoming state, write sr*y.
__global__ __launch_bounds__(256) void wkv_p3(const float* __restrict__ td,
                                              const float* __restrict__ tf,
                                              const short* __restrict__ K,
                                              const short* __restrict__ V,
                                              const short* __restrict__ SR,
                                              short* __restrict__ SRY,
                                              const float* __restrict__ Aa,
                                              const float* __restrict__ Ba,
                                              const float* __restrict__ Pa) {
  int bx = blockIdx.x;
  int ch = bx >> 5;
  int b = (bx >> 2) & 7;
  int c = (bx & 3) * 256 + threadIdx.x;
  float w = -expf(td[c]);
  float u = tf[c];
  int idx = ch * 8192 + b * 1024 + c;
  float aa = Aa[idx], bb = Ba[idx], pp = Pa[idx];
  int64_t base = ((int64_t)b * TT_ + ch * WKV_L) * TC_ + c;
#pragma unroll
  for (int t = 0; t < WKV_L; ++t) {
    int64_t o = base + (int64_t)t * TC_;
    float kt = b2f(K[o]), vt = b2f(V[o]);
    float ww = u + kt;
    float p = fmaxf(pp, ww);
    float E1 = expf(pp - p);
    float E2 = expf(ww - p);
    float y = (E1 * aa + E2 * vt) / (E1 * bb + E2);
    SRY[o] = f2b(y * b2f(SR[o]));
    float ww2 = pp + w;
    float p2 = fmaxf(ww2, kt);
    float e1 = expf(ww2 - p2);
    float e2 = expf(kt - p2);
    aa = e1 * aa + e2 * vt;
    bb = e1 * bb + e2;
    pp = p2;
  }
}

// S[c] = sum_j Wam[c][j] (j<256)
__global__ __launch_bounds__(64) void row_sum256(const float* __restrict__ Wam,
                                                 float* __restrict__ S) {
  int c = blockIdx.x;
  int lane = threadIdx.x;
  float4 v = ((const float4*)(Wam + (int64_t)c * 256))[lane];
  float s = v.x + v.y + v.z + v.w;
  for (int off = 32; off > 0; off >>= 1) s += __shfl_down(s, off);
  if (lane == 0) S[c] = s;
}

// ---------------- bf16 MFMA GEMM ----------------
// C[bz][m][n] = epi( sum_k A[m][k]*B[n][k] ), A: M x K bf16, B: N x K bf16.
// 128x128 tile, BK=32, 256 threads (4 waves, 2x2), 4x4 frags of 16x16x32/wave.
template <int EPI>
__global__ __launch_bounds__(256, 2) void gemm_bf16(
    const short* __restrict__ A, const short* __restrict__ B,
    void* __restrict__ Cp, int M, int N, int K,
    int64_t sA, int64_t sB, int64_t sC,
    const float* __restrict__ e0, const float* __restrict__ e1,
    const float* __restrict__ e2, const void* __restrict__ e3, int64_t sE) {
  __shared__ short lds[8192];  // A: [0,4096) shorts, B: [4096,8192)
  const int tid = threadIdx.x;
  const int bz = blockIdx.z;
  const int brow = blockIdx.y * 128;
  const int bcol = blockIdx.x * 128;
  const short* Ab = A + bz * sA;
  const short* Bb = B + bz * sB;

  const short* gA0 = Ab + (int64_t)(brow + (tid >> 2)) * K + (tid & 3) * 8;
  const short* gA1 = Ab + (int64_t)(brow + 64 + (tid >> 2)) * K + (tid & 3) * 8;
  const short* gB0 = Bb + (int64_t)(bcol + (tid >> 2)) * K + (tid & 3) * 8;
  const short* gB1 = Bb + (int64_t)(bcol + 64 + (tid >> 2)) * K + (tid & 3) * 8;
  short* lA0 = &lds[tid * 8];
  short* lA1 = &lds[2048 + tid * 8];
  short* lB0 = &lds[4096 + tid * 8];
  short* lB1 = &lds[6144 + tid * 8];

  const int lane = tid & 63, wid = tid >> 6;
  const int wr = wid >> 1, wc = wid & 1;
  const short* aPtr = lds + (wr * 64 + (lane & 15)) * 32 + (lane >> 4) * 8;
  const short* bPtr = lds + 4096 + (wc * 64 + (lane & 15)) * 32 + (lane >> 4) * 8;

  f32x4 acc[4][4] = {};
  for (int k0 = 0; k0 < K; k0 += 32) {
    gload16(gA0 + k0, lA0);
    gload16(gA1 + k0, lA1);
    gload16(gB0 + k0, lB0);
    gload16(gB1 + k0, lB1);
    __syncthreads();
    bf16x8 af[4], bfv[4];
#pragma unroll
    for (int m = 0; m < 4; ++m) af[m] = *(const bf16x8*)(aPtr + m * 512);
#pragma unroll
    for (int n = 0; n < 4; ++n) bfv[n] = *(const bf16x8*)(bPtr + n * 512);
#pragma unroll
    for (int m = 0; m < 4; ++m)
#pragma unroll
      for (int n = 0; n < 4; ++n)
        acc[m][n] = __builtin_amdgcn_mfma_f32_16x16x32_bf16(af[m], bfv[n],
                                                            acc[m][n], 0, 0, 0);
    __syncthreads();
  }

  const int r0 = brow + wr * 64 + (lane >> 4) * 4;
  const int c0 = bcol + wc * 64 + (lane & 15);
#pragma unroll
  for (int m = 0; m < 4; ++m) {
#pragma unroll
    for (int j = 0; j < 4; ++j) {
      int row = r0 + m * 16 + j;
#pragma unroll
      for (int n = 0; n < 4; ++n) {
        int col = c0 + n * 16;
        float v = acc[m][n][j];
        int64_t idx = (int64_t)row * N + col;
        if (EPI == 0) {
          ((short*)Cp)[bz * sC + idx] = f2b(v);
        } else if (EPI == 1) {
          ((short*)Cp)[bz * sC + idx] = f2b(sigm(v));
        } else if (EPI == 2) {
          v = fmaxf(v, 0.0f);
          ((short*)Cp)[bz * sC + idx] = f2b(v * v);
        } else if (EPI == 3) {
          float r2 = v + e0[row] * e1[col] + e2[col];
          float xo = ((const float*)e3)[bz * sE + idx];
          ((float*)Cp)[bz * sC + idx] = xo * (1.0f + r2);
        } else if (EPI == 4) {
          float* XC = (float*)Cp;
          XC[idx] = XC[idx] + lif4(v);
        } else if (EPI == 5) {
          float* XC = (float*)Cp;
          float srr = b2f(((const short*)e3)[idx]);
          XC[idx] = XC[idx] + lif4(v * srr);
        }
      }
    }
  }
}

// ---------------- launch ----------------
extern "C" void kernel_launch(void* const* d_in, const int* in_sizes, int n_in,
                              void* d_out, int out_size, void* d_ws,
                              size_t ws_size, hipStream_t stream) {
  const float* x   = (const float*)d_in[0];
  const float* rt  = (const float*)d_in[1];
  const float* td  = (const float*)d_in[2];
  const float* tf  = (const float*)d_in[3];
  const float* tmk = (const float*)d_in[4];
  const float* tmv = (const float*)d_in[5];
  const float* tmr = (const float*)d_in[6];
  const float* Wk  = (const float*)d_in[7];
  const float* Wv  = (const float*)d_in[8];
  const float* Wr  = (const float*)d_in[9];
  const float* Wo  = (const float*)d_in[10];
  const float* cmk = (const float*)d_in[11];
  const float* cmr = (const float*)d_in[12];
  const float* Wck = (const float*)d_in[13];
  const float* Wcv = (const float*)d_in[14];
  const float* Wcr = (const float*)d_in[15];
  const float* Wrm = (const float*)d_in[16];
  const float* brm = (const float*)d_in[17];
  const float* Wam = (const float*)d_in[18];
  const float* bam = (const float*)d_in[19];
  float* out = (float*)d_out;

  const size_t MB = 1ull << 20;
  uint8_t* W8 = (uint8_t*)d_ws;
  float* XC  = (float*)(W8);                 // 16 MB f32 residual
  short* L   = (short*)(W8 + 16 * MB);       // 8 MB bf16 slots
  short* S1  = (short*)(W8 + 24 * MB);
  short* S2  = (short*)(W8 + 32 * MB);
  short* S3  = (short*)(W8 + 40 * MB);
  short* S4  = (short*)(W8 + 48 * MB);
  short* bWk  = (short*)(W8 + 56 * MB);      // time-mix weights (2 MB each)
  short* bWv  = (short*)(W8 + 58 * MB);
  short* bWr  = (short*)(W8 + 60 * MB);
  short* bWo  = (short*)(W8 + 62 * MB);
  short* bWcr = (short*)(W8 + 64 * MB);
  short* bWrm = (short*)(W8 + 66 * MB);               // 0.5 MB
  short* bWam = (short*)(W8 + 66 * MB + 512 * 1024);  // 0.5 MB
  short* bWck = bWk;                         // overwrites bWk..bWo (8 MB) later
  short* bWcv = S4;                          // reuses slot S4 later
  short* H16  = (short*)(W8 + 67 * MB);      // 32 MB bf16 (4096x4096)
  // wkv scan temporaries live in the (currently dead) H16 region: 6 MB
  float* Ca = (float*)(W8 + 67 * MB);
  float* Da = (float*)(W8 + 68 * MB);
  float* Qa = (float*)(W8 + 69 * MB);
  float* Aa = (float*)(W8 + 70 * MB);
  float* Ba = (float*)(W8 + 71 * MB);
  float* Pa = (float*)(W8 + 72 * MB);
  float* Sb   = (float*)(W8 + 99 * MB);      // 4 KB

  dim3 blk(256);
  const int NV4 = 4096;   // B*T*C/4 / 256
  const int NV8 = 2048;   // B*T*C/8 / 256

  // weight conversions needed for time-mix + tail
  cvt_b<<<512, blk, 0, stream>>>(Wk, bWk);
  cvt_b<<<512, blk, 0, stream>>>(Wv, bWv);
  cvt_b<<<512, blk, 0, stream>>>(Wr, bWr);
  cvt_b<<<512, blk, 0, stream>>>(Wo, bWo);
  cvt_b<<<512, blk, 0, stream>>>(Wcr, bWcr);
  cvt_b<<<128, blk, 0, stream>>>(Wrm, bWrm);
  cvt_b<<<128, blk, 0, stream>>>(Wam, bWam);

  // 1) xc = concat(x, rt); ln1 -> L; mixes -> S1,S2,S3
  build_xc<<<NV4, blk, 0, stream>>>(x, rt, XC);
  ln_rows_b<<<TB_ * TT_, blk, 0, stream>>>(XC, L);
  mix3_b<<<NV8, blk, 0, stream>>>(L, tmk, tmv, tmr, S1, S2, S3);

  // 2) K = S1*Wk^T -> S4 ; V = S2*Wv^T -> S1 ; SR = sigm(S3*Wr^T) -> S2
  dim3 gMain(1024 / 128, 4096 / 128, 1);
  gemm_bf16<0><<<gMain, blk, 0, stream>>>(S1, bWk, S4, 4096, 1024, 1024, 0, 0, 0,
                                          nullptr, nullptr, nullptr, nullptr, 0);
  gemm_bf16<0><<<gMain, blk, 0, stream>>>(S2, bWv, S1, 4096, 1024, 1024, 0, 0, 0,
                                          nullptr, nullptr, nullptr, nullptr, 0);
  gemm_bf16<1><<<gMain, blk, 0, stream>>>(S3, bWr, S2, 4096, 1024, 1024, 0, 0, 0,
                                          nullptr, nullptr, nullptr, nullptr, 0);
  // 3) wkv chunked scan: K=S4, V=S1, SR=S2 -> SRY in L
  wkv_p1<<<WKV_NCH * TB_ * 4, blk, 0, stream>>>(td, S4, S1, Ca, Da, Qa);
  wkv_p2<<<32, blk, 0, stream>>>(td, Ca, Da, Qa, Aa, Ba, Pa);
  wkv_p3<<<WKV_NCH * TB_ * 4, blk, 0, stream>>>(td, tf, S4, S1, S2, L, Aa, Ba,
                                                Pa);
  // 4) att: XC += lif(L*Wo^T)
  gemm_bf16<4><<<gMain, blk, 0, stream>>>(L, bWo, XC, 4096, 1024, 1024, 0, 0, 0,
                                          nullptr, nullptr, nullptr, nullptr, 0);
  // 5) ln2 -> L; mix2 -> S1(xk2), S2(xr2)
  ln_rows_b<<<TB_ * TT_, blk, 0, stream>>>(XC, L);
  mix2_b<<<NV8, blk, 0, stream>>>(L, cmk, cmr, S1, S2);
  // 6) SRR = sigm(S2*Wcr^T) -> S3
  gemm_bf16<1><<<gMain, blk, 0, stream>>>(S2, bWcr, S3, 4096, 1024, 1024, 0, 0, 0,
                                          nullptr, nullptr, nullptr, nullptr, 0);
  // 7) convert channel-mix weights into now-dead regions
  cvt_b<<<2048, blk, 0, stream>>>(Wck, bWck);
  cvt_b<<<2048, blk, 0, stream>>>(Wcv, bWcv);
  // 8) H = relu^2(S1*Wck^T) -> H16 (4096x4096)
  gemm_bf16<2><<<dim3(32, 32, 1), blk, 0, stream>>>(
      S1, bWck, H16, 4096, 4096, 1024, 0, 0, 0, nullptr, nullptr, nullptr,
      nullptr, 0);
  // 9) XC += lif(SRR * (H*Wcv^T))
  gemm_bf16<5><<<dim3(8, 32, 1), blk, 0, stream>>>(
      H16, bWcv, XC, 4096, 1024, 4096, 0, 0, 0, nullptr, nullptr, nullptr, S3,
      0);
  // 10) tail
  cvt_rtok<<<1024, blk, 0, stream>>>(XC, S1);
  gemm_bf16<0><<<dim3(2, 2, 8), blk, 0, stream>>>(
      bWrm, S1, S2, 256, 256, 1024, 0, (int64_t)256 * 1024, (int64_t)256 * 256,
      nullptr, nullptr, nullptr, nullptr, 0);
  row_sum256<<<1024, dim3(64), 0, stream>>>(Wam, Sb);
  gemm_bf16<3><<<dim3(8, 2, 8), blk, 0, stream>>>(
      S2, bWam, out, 256, 1024, 256, (int64_t)256 * 256, 0,
      (int64_t)256 * 1024, brm, Sb, bam, XC, (int64_t)512 * 1024);
}